// Round 3
// baseline (262.751 us; speedup 1.0000x reference)
//
#include <hip/hip_runtime.h>
#include <math.h>

// Problem constants
#define T_LEN 2048
#define BB    8
#define RS    256
#define DIN   1024
#define NE    768                 // 256 (W_proj) + 512 (W_res)
#define M_TOT (BB * T_LEN)        // 16384
#define LCH   32                  // scan chunk length
#define NCH   (T_LEN / LCH)       // 64 chunks
#define OUT_MAIN (M_TOT * 512)    // 8388608 floats, then final_r (2048), final_i (2048)

typedef unsigned short ushort;
typedef unsigned int   uint;
typedef short  short8  __attribute__((ext_vector_type(8)));
typedef float  f32x16  __attribute__((ext_vector_type(16)));
typedef ushort ushort8 __attribute__((ext_vector_type(8)));

// round-to-nearest-even fp32 -> bf16 bits
__device__ __forceinline__ ushort f2bf_rn(float x) {
    uint u = __float_as_uint(x);
    return (ushort)((u + 0x7FFFu + ((u >> 16) & 1u)) >> 16);
}
__device__ __forceinline__ float bf2f(ushort b) {
    return __uint_as_float(((uint)b) << 16);
}

// async global->LDS, 16 bytes per lane (lane-linear LDS dest required)
__device__ __forceinline__ void gload16(const ushort* g, ushort* l) {
    __builtin_amdgcn_global_load_lds(
        (const __attribute__((address_space(1))) uint*)g,
        (__attribute__((address_space(3))) uint*)l, 16, 0, 0);
}

// ---------------------------------------------------------------------------
// K0: fused split fp32 -> bf16 hi/lo for U, W_proj, W_res in one launch.
//     One 8-float group per thread.
// ---------------------------------------------------------------------------
#define N8U  (M_TOT * DIN / 8)        // 2097152
#define N8WP (RS * DIN / 8)           // 32768
#define N8WR (2 * RS * DIN / 8)       // 65536
#define N8TOT (N8U + N8WP + N8WR)     // 2195456 = 8576 * 256

__global__ __launch_bounds__(256) void split_kernel(
    const float* __restrict__ u, const float* __restrict__ wp,
    const float* __restrict__ wr, ushort* __restrict__ Uhi,
    ushort* __restrict__ Ulo, ushort* __restrict__ Whi, ushort* __restrict__ Wlo)
{
    const int i = blockIdx.x * 256 + threadIdx.x;
    if (i >= N8TOT) return;
    const float* src; ushort* hi; ushort* lo; int j;
    if (i < N8U)              { src = u;  hi = Uhi; lo = Ulo; j = i; }
    else if (i < N8U + N8WP)  { src = wp; hi = Whi; lo = Wlo; j = i - N8U; }
    else                      { src = wr; hi = Whi + (size_t)RS * DIN;
                                lo = Wlo + (size_t)RS * DIN; j = i - N8U - N8WP; }
    const float4 x0 = ((const float4*)src)[(size_t)j * 2 + 0];
    const float4 x1 = ((const float4*)src)[(size_t)j * 2 + 1];
    const float xs[8] = {x0.x, x0.y, x0.z, x0.w, x1.x, x1.y, x1.z, x1.w};
    ushort8 hv, lv;
#pragma unroll
    for (int k = 0; k < 8; ++k) {
        const ushort hb = f2bf_rn(xs[k]);
        hv[k] = hb;
        lv[k] = f2bf_rn(xs[k] - bf2f(hb));
    }
    ((ushort8*)hi)[j] = hv;
    ((ushort8*)lo)[j] = lv;
}

// ---------------------------------------------------------------------------
// K1: bf16 3-term split MFMA GEMM, 32x32x16 fragments.
//     128x128 tile, BK=32, 4 waves (2x2), per-wave 2x2 frags of 32x32.
//     Double-buffered LDS (64 KB), prefetch-next-tile before compute
//     (T3-minimum 2-phase), k-blocked LDS layout [kblk][128][8] per plane.
//     1D grid 768 with bijective XCD swizzle (768 = 8 * 96).
// ---------------------------------------------------------------------------
#define BKK 32
#define KTILES (DIN / BKK)   // 32

__global__ __launch_bounds__(256) void gemm_mfma(
    const ushort* __restrict__ Uh, const ushort* __restrict__ Ul,
    const ushort* __restrict__ Wh, const ushort* __restrict__ Wl,
    float* __restrict__ C)
{
    // [buf][plane(Ah,Al,Bh,Bl)][kblk*128rows*8elem]  = 2*4*4096 ushort = 64 KB
    __shared__ ushort lds[2][4][4096];
    const int tid  = threadIdx.x;
    const int id   = blockIdx.x;
    const int sid  = (id & 7) * 96 + (id >> 3);    // XCD-contiguous, bijective
    const int bn   = sid % 6;
    const int bm   = sid / 6;
    const int wid  = tid >> 6;
    const int lane = tid & 63;
    const int wr   = wid >> 1, wc = wid & 1;
    const int l31  = lane & 31;
    const int lh   = lane >> 5;                    // k-half selector

    // staging: thread t covers (kblk = t>>7 [+2 for q=1], row = t&127), 8 elems
    const int srow = tid & 127;
    const int kb0  = tid >> 7;
    const size_t arow = (size_t)(bm * 128 + srow) * DIN + kb0 * 8;
    const size_t brow = (size_t)(bn * 128 + srow) * DIN + kb0 * 8;
    const ushort* gsrc[4] = { Uh + arow, Ul + arow, Wh + brow, Wl + brow };
    const int lslot0 = tid * 8;             // q=0 LDS elem offset
    const int lslot1 = (256 + tid) * 8;     // q=1

    f32x16 acc[2][2];
#pragma unroll
    for (int m = 0; m < 2; ++m)
#pragma unroll
        for (int n = 0; n < 2; ++n)
#pragma unroll
            for (int j = 0; j < 16; ++j) acc[m][n][j] = 0.f;

    // prologue: stage tile 0 into buf 0
#pragma unroll
    for (int p = 0; p < 4; ++p) {
        gload16(gsrc[p],      &lds[0][p][lslot0]);
        gload16(gsrc[p] + 16, &lds[0][p][lslot1]);
    }
    __syncthreads();

    int bufc = 0;
    for (int kt = 0; kt < KTILES; ++kt) {
        const int kk = kt * BKK;
        if (kt + 1 < KTILES) {   // prefetch next K-tile into other buffer
#pragma unroll
            for (int p = 0; p < 4; ++p) {
                gload16(gsrc[p] + kk + BKK,      &lds[bufc ^ 1][p][lslot0]);
                gload16(gsrc[p] + kk + BKK + 16, &lds[bufc ^ 1][p][lslot1]);
            }
        }
        // compute current buffer: 2 k-steps of 16, 3-term split
#pragma unroll
        for (int t2 = 0; t2 < 2; ++t2) {
            const int kblk = t2 * 2 + lh;
            short8 ah[2], al[2], bh[2], bl[2];
#pragma unroll
            for (int m = 0; m < 2; ++m) {
                const int row = wr * 64 + m * 32 + l31;
                ah[m] = *(const short8*)&lds[bufc][0][kblk * 1024 + row * 8];
                al[m] = *(const short8*)&lds[bufc][1][kblk * 1024 + row * 8];
            }
#pragma unroll
            for (int n = 0; n < 2; ++n) {
                const int col = wc * 64 + n * 32 + l31;
                bh[n] = *(const short8*)&lds[bufc][2][kblk * 1024 + col * 8];
                bl[n] = *(const short8*)&lds[bufc][3][kblk * 1024 + col * 8];
            }
#pragma unroll
            for (int m = 0; m < 2; ++m)
#pragma unroll
                for (int n = 0; n < 2; ++n) {
                    acc[m][n] = __builtin_amdgcn_mfma_f32_32x32x16_bf16(ah[m], bh[n], acc[m][n], 0, 0, 0);
                    acc[m][n] = __builtin_amdgcn_mfma_f32_32x32x16_bf16(ah[m], bl[n], acc[m][n], 0, 0, 0);
                    acc[m][n] = __builtin_amdgcn_mfma_f32_32x32x16_bf16(al[m], bh[n], acc[m][n], 0, 0, 0);
                }
        }
        __syncthreads();   // drains prefetch (vmcnt 0) + readers done
        bufc ^= 1;
    }

    // epilogue: 32x32 C/D layout: col=lane&31, row=(j&3)+8*(j>>2)+4*(lane>>5)
    const int crow0 = bm * 128 + wr * 64;
    const int ccol0 = bn * 128 + wc * 64 + l31;
#pragma unroll
    for (int m = 0; m < 2; ++m)
#pragma unroll
        for (int n = 0; n < 2; ++n) {
            const int col = ccol0 + n * 32;
#pragma unroll
            for (int j = 0; j < 16; ++j) {
                const int row = crow0 + m * 32 + (j & 3) + 8 * (j >> 2) + 4 * lh;
                C[(size_t)row * NE + col] = acc[m][n][j];
            }
        }
}

// ---------------------------------------------------------------------------
// complex pole per state r:  z = exp(lam) * (cos w, sin w),  lam = -5*sigmoid(lraw)
// ---------------------------------------------------------------------------
__device__ inline void pole(const float* __restrict__ lraw, const float* __restrict__ om,
                            int r, float& zr, float& zi, float& lam, float& o)
{
    const float x   = lraw[r];
    const float sig = 1.f / (1.f + expf(-x));
    lam = -5.f * sig;
    o   = om[r];
    const float er = expf(lam);
    zr = er * cosf(o);
    zi = er * sinf(o);
}

// ---------------------------------------------------------------------------
// K2: per-chunk carries — no LDS, direct coalesced strided reads, unroll-8.
// ---------------------------------------------------------------------------
__global__ __launch_bounds__(256) void carry_kernel(
    const float* __restrict__ C, const float* __restrict__ lraw,
    const float* __restrict__ om, float2* __restrict__ carry)
{
    const int c = blockIdx.x, b = blockIdx.y, r = threadIdx.x;
    const int m0 = b * T_LEN + c * LCH;
    float zr, zi, lam, o;
    pole(lraw, om, r, zr, zi, lam, o);
    const float* p = C + (size_t)m0 * NE + r;
    float hr = 0.f, hi = 0.f;
#pragma unroll 8
    for (int s = 0; s < LCH; ++s) {
        const float u  = p[(size_t)s * NE];
        const float nr = zr * hr - zi * hi + u;
        const float ni = zr * hi + zi * hr;
        hr = nr; hi = ni;
    }
    carry[(size_t)(b * NCH + c) * RS + r] = make_float2(hr, hi);
}

// ---------------------------------------------------------------------------
// K3: prefix over chunks per (b, r), carries bulk-staged through LDS in two
//     64 KB halves to avoid a serial-HBM-latency chain. Writes final_r/final_i.
// ---------------------------------------------------------------------------
__global__ __launch_bounds__(256) void chunk_scan_kernel(
    const float2* __restrict__ carry, const float* __restrict__ h0r,
    const float* __restrict__ h0i, const float* __restrict__ lraw,
    const float* __restrict__ om, float2* __restrict__ S, float* __restrict__ out)
{
    const int b = blockIdx.x, r = threadIdx.x;
    __shared__ float2 cs[32 * RS];   // 64 KB
    float zr, zi, lam, o;
    pole(lraw, om, r, zr, zi, lam, o);
    const float eL  = expf(lam * (float)LCH);
    const float zLr = eL * cosf(o * (float)LCH);
    const float zLi = eL * sinf(o * (float)LCH);
    float sr = h0r[b * RS + r];
    float si = h0i[b * RS + r];
    for (int half = 0; half < 2; ++half) {
        __syncthreads();   // protect cs reuse across halves
        const float4* src = (const float4*)(carry + ((size_t)b * NCH + half * 32) * RS);
        float4* dst = (float4*)cs;
        for (int i = r; i < 32 * RS / 2; i += 256) dst[i] = src[i];
        __syncthreads();
        for (int cc = 0; cc < 32; ++cc) {
            const int c = half * 32 + cc;
            S[((size_t)b * NCH + c) * RS + r] = make_float2(sr, si);
            const float2 k = cs[cc * RS + r];
            const float nr = zLr * sr - zLi * si + k.x;
            const float ni = zLr * si + zLi * sr + k.y;
            sr = nr; si = ni;
        }
    }
    out[OUT_MAIN + b * RS + r]           = sr;   // final_r
    out[OUT_MAIN + BB * RS + b * RS + r] = si;   // final_i
}

// ---------------------------------------------------------------------------
// K4: re-scan chunk + residual + LayerNorm, batched 8 rows per barrier pair.
//     Scan phase: thread=r computes x into LDS. LN phase: wave w owns rows
//     w*2, w*2+1; lane-local 8-elem partials + 6-step shfl tree; float4 stores.
// ---------------------------------------------------------------------------
__global__ __launch_bounds__(256) void scan_ln_kernel(
    const float* __restrict__ C, const float2* __restrict__ S,
    const float* __restrict__ lraw, const float* __restrict__ om,
    const float* __restrict__ gamma, const float* __restrict__ beta,
    float* __restrict__ out)
{
    const int c = blockIdx.x, b = blockIdx.y, r = threadIdx.x;
    __shared__ float xt[8][512];
    const int m0 = b * T_LEN + c * LCH;
    float zr, zi, lam, o;
    pole(lraw, om, r, zr, zi, lam, o);
    float2 st = S[(size_t)(b * NCH + c) * RS + r];
    const int wid = r >> 6, lane = r & 63;
    // per-lane gamma/beta for LN phase (channels lane*8 .. lane*8+7)
    const float4 g0  = *(const float4*)&gamma[lane * 8];
    const float4 g1  = *(const float4*)&gamma[lane * 8 + 4];
    const float4 be0 = *(const float4*)&beta[lane * 8];
    const float4 be1 = *(const float4*)&beta[lane * 8 + 4];

    for (int batch = 0; batch < 4; ++batch) {
        const int s0 = batch * 8;
#pragma unroll
        for (int s = 0; s < 8; ++s) {
            const int m = m0 + s0 + s;
            const float u  = C[(size_t)m * NE + r];
            const float hr = zr * st.x - zi * st.y + u;
            const float hi = zr * st.y + zi * st.x;
            st.x = hr; st.y = hi;
            xt[s][r]       = hr + C[(size_t)m * NE + 256 + r];
            xt[s][256 + r] = hi + C[(size_t)m * NE + 512 + r];
        }
        __syncthreads();
#pragma unroll
        for (int rr = 0; rr < 2; ++rr) {
            const int s = wid * 2 + rr;
            const int m = m0 + s0 + s;
            const float4 x0 = *(const float4*)&xt[s][lane * 8];
            const float4 x1 = *(const float4*)&xt[s][lane * 8 + 4];
            float s1 = (x0.x + x0.y) + (x0.z + x0.w) + (x1.x + x1.y) + (x1.z + x1.w);
            float s2 = (x0.x * x0.x + x0.y * x0.y) + (x0.z * x0.z + x0.w * x0.w)
                     + (x1.x * x1.x + x1.y * x1.y) + (x1.z * x1.z + x1.w * x1.w);
#pragma unroll
            for (int off = 1; off < 64; off <<= 1) {
                s1 += __shfl_xor(s1, off);
                s2 += __shfl_xor(s2, off);
            }
            const float mu   = s1 * (1.f / 512.f);
            const float var  = s2 * (1.f / 512.f) - mu * mu;
            const float rstd = rsqrtf(var + 1e-5f);
            float4 o0, o1;
            o0.x = (x0.x - mu) * rstd * g0.x + be0.x;
            o0.y = (x0.y - mu) * rstd * g0.y + be0.y;
            o0.z = (x0.z - mu) * rstd * g0.z + be0.z;
            o0.w = (x0.w - mu) * rstd * g0.w + be0.w;
            o1.x = (x1.x - mu) * rstd * g1.x + be1.x;
            o1.y = (x1.y - mu) * rstd * g1.y + be1.y;
            o1.z = (x1.z - mu) * rstd * g1.z + be1.z;
            o1.w = (x1.w - mu) * rstd * g1.w + be1.w;
            *(float4*)&out[(size_t)m * 512 + lane * 8]     = o0;
            *(float4*)&out[(size_t)m * 512 + lane * 8 + 4] = o1;
        }
        __syncthreads();   // xt reuse next batch
    }
}

// ---------------------------------------------------------------------------
extern "C" void kernel_launch(void* const* d_in, const int* in_sizes, int n_in,
                              void* d_out, int out_size, void* d_ws, size_t ws_size,
                              hipStream_t stream)
{
    const float* u    = (const float*)d_in[0];
    const float* h0r  = (const float*)d_in[1];
    const float* h0i  = (const float*)d_in[2];
    const float* lraw = (const float*)d_in[3];
    const float* omg  = (const float*)d_in[4];
    const float* Wp   = (const float*)d_in[5];
    const float* Wr   = (const float*)d_in[6];
    const float* gam  = (const float*)d_in[7];
    const float* bet  = (const float*)d_in[8];
    float* out = (float*)d_out;

    // workspace layout (~123 MB):
    float*  C     = (float*)d_ws;                       // 16384*768 f32 (50.3 MB)
    float2* carry = (float2*)(C + (size_t)M_TOT * NE);  // 1 MB
    float2* S     = carry + (size_t)BB * NCH * RS;      // 1 MB
    ushort* Uhi   = (ushort*)(S + (size_t)BB * NCH * RS);
    ushort* Ulo   = Uhi + (size_t)M_TOT * DIN;          // 33.5 MB each
    ushort* Whi   = Ulo + (size_t)M_TOT * DIN;          // 1.57 MB
    ushort* Wlo   = Whi + (size_t)NE * DIN;             // 1.57 MB

    split_kernel<<<N8TOT / 256, 256, 0, stream>>>(u, Wp, Wr, Uhi, Ulo, Whi, Wlo);
    gemm_mfma<<<768, 256, 0, stream>>>(Uhi, Ulo, Whi, Wlo, C);
    carry_kernel<<<dim3(NCH, BB), 256, 0, stream>>>(C, lraw, omg, carry);
    chunk_scan_kernel<<<BB, 256, 0, stream>>>(carry, h0r, h0i, lraw, omg, S, out);
    scan_ln_kernel<<<dim3(NCH, BB), 256, 0, stream>>>(C, (const float2*)S, lraw, omg, gam, bet, out);
}

// Round 4
// 258.560 us; speedup vs baseline: 1.0162x; 1.0162x over previous
//
#include <hip/hip_runtime.h>
#include <math.h>

// Problem constants
#define T_LEN 2048
#define BB    8
#define RS    256
#define DIN   1024
#define NE    768                 // 256 (W_proj) + 512 (W_res)
#define M_TOT (BB * T_LEN)        // 16384
#define LCH   32                  // scan chunk length
#define NCH   (T_LEN / LCH)       // 64 chunks
#define OUT_MAIN (M_TOT * 512)    // 8388608 floats, then final_r (2048), final_i (2048)

typedef unsigned short ushort;
typedef unsigned int   uint;
typedef short  short8  __attribute__((ext_vector_type(8)));
typedef float  f32x4   __attribute__((ext_vector_type(4)));
typedef ushort ushort8 __attribute__((ext_vector_type(8)));

// round-to-nearest-even fp32 -> bf16 bits
__device__ __forceinline__ ushort f2bf_rn(float x) {
    uint u = __float_as_uint(x);
    return (ushort)((u + 0x7FFFu + ((u >> 16) & 1u)) >> 16);
}
__device__ __forceinline__ float bf2f(ushort b) {
    return __uint_as_float(((uint)b) << 16);
}

// async global->LDS, 16 bytes per lane (lane-linear LDS dest required)
__device__ __forceinline__ void gload16(const ushort* g, ushort* l) {
    __builtin_amdgcn_global_load_lds(
        (const __attribute__((address_space(1))) uint*)g,
        (__attribute__((address_space(3))) uint*)l, 16, 0, 0);
}

// ---------------------------------------------------------------------------
// K0: fused split fp32 -> bf16 hi/lo for U, W_proj, W_res in one launch.
// ---------------------------------------------------------------------------
#define N8U  (M_TOT * DIN / 8)        // 2097152
#define N8WP (RS * DIN / 8)           // 32768
#define N8WR (2 * RS * DIN / 8)       // 65536
#define N8TOT (N8U + N8WP + N8WR)     // 2195456 = 8576 * 256

__global__ __launch_bounds__(256) void split_kernel(
    const float* __restrict__ u, const float* __restrict__ wp,
    const float* __restrict__ wr, ushort* __restrict__ Uhi,
    ushort* __restrict__ Ulo, ushort* __restrict__ Whi, ushort* __restrict__ Wlo)
{
    const int i = blockIdx.x * 256 + threadIdx.x;
    if (i >= N8TOT) return;
    const float* src; ushort* hi; ushort* lo; int j;
    if (i < N8U)              { src = u;  hi = Uhi; lo = Ulo; j = i; }
    else if (i < N8U + N8WP)  { src = wp; hi = Whi; lo = Wlo; j = i - N8U; }
    else                      { src = wr; hi = Whi + (size_t)RS * DIN;
                                lo = Wlo + (size_t)RS * DIN; j = i - N8U - N8WP; }
    const float4 x0 = ((const float4*)src)[(size_t)j * 2 + 0];
    const float4 x1 = ((const float4*)src)[(size_t)j * 2 + 1];
    const float xs[8] = {x0.x, x0.y, x0.z, x0.w, x1.x, x1.y, x1.z, x1.w};
    ushort8 hv, lv;
#pragma unroll
    for (int k = 0; k < 8; ++k) {
        const ushort hb = f2bf_rn(xs[k]);
        hv[k] = hb;
        lv[k] = f2bf_rn(xs[k] - bf2f(hb));
    }
    ((ushort8*)hi)[j] = hv;
    ((ushort8*)lo)[j] = lv;
}

// ---------------------------------------------------------------------------
// K1: bf16 3-term split MFMA GEMM — R2 version (measured 90 us, 859 TF eff).
//     m97 structure: 128x128 tile, BK=32, 4 waves (2x2), 4x4 16x16x32 frags,
//     global_load_lds width=16 staging, 2-barrier K-loop, 32 KB LDS.
// ---------------------------------------------------------------------------
#define Bb 128
#define BK 32

__global__ __launch_bounds__(256) void gemm_mfma(
    const ushort* __restrict__ Uh, const ushort* __restrict__ Ul,
    const ushort* __restrict__ Wh, const ushort* __restrict__ Wl,
    float* __restrict__ C)
{
    __shared__ ushort Ah[Bb * BK], Al[Bb * BK], Bh[Bb * BK], Bl[Bb * BK];
    const int tid  = threadIdx.x;
    const int bn   = blockIdx.x;          // 0..5
    const int bm   = blockIdx.y;          // 0..127
    const int wid  = tid >> 6;
    const int lane = tid & 63;
    const int wr   = wid >> 1, wc = wid & 1;
    const int fr   = lane & 15;           // row/col within fragment
    const int fq   = lane >> 4;           // k-chunk 0..3

    const int srow = tid >> 2;            // 0..63
    const int skk  = (tid & 3) * 8;
    const ushort* gAh = Uh + (size_t)(bm * 128 + srow) * DIN + skk;
    const ushort* gAl = Ul + (size_t)(bm * 128 + srow) * DIN + skk;
    const ushort* gBh = Wh + (size_t)(bn * 128 + srow) * DIN + skk;
    const ushort* gBl = Wl + (size_t)(bn * 128 + srow) * DIN + skk;
    ushort* lAh0 = Ah + tid * 8; ushort* lAh1 = Ah + 64 * BK + tid * 8;
    ushort* lAl0 = Al + tid * 8; ushort* lAl1 = Al + 64 * BK + tid * 8;
    ushort* lBh0 = Bh + tid * 8; ushort* lBh1 = Bh + 64 * BK + tid * 8;
    ushort* lBl0 = Bl + tid * 8; ushort* lBl1 = Bl + 64 * BK + tid * 8;
    const size_t rstep = (size_t)64 * DIN;

    f32x4 acc[4][4];
#pragma unroll
    for (int m = 0; m < 4; ++m)
#pragma unroll
        for (int n = 0; n < 4; ++n) acc[m][n] = (f32x4){0.f, 0.f, 0.f, 0.f};

    for (int kk = 0; kk < DIN; kk += BK) {
        gload16(gAh + kk, lAh0); gload16(gAh + kk + rstep, lAh1);
        gload16(gAl + kk, lAl0); gload16(gAl + kk + rstep, lAl1);
        gload16(gBh + kk, lBh0); gload16(gBh + kk + rstep, lBh1);
        gload16(gBl + kk, lBl0); gload16(gBl + kk + rstep, lBl1);
        __syncthreads();   // drains vmcnt (compiler-emitted) — tiles ready

        short8 ah[4], al[4], bh[4], bl[4];
#pragma unroll
        for (int m = 0; m < 4; ++m) {
            const int row = wr * 64 + m * 16 + fr;
            ah[m] = *(const short8*)&Ah[row * BK + fq * 8];
            al[m] = *(const short8*)&Al[row * BK + fq * 8];
        }
#pragma unroll
        for (int n = 0; n < 4; ++n) {
            const int col = wc * 64 + n * 16 + fr;
            bh[n] = *(const short8*)&Bh[col * BK + fq * 8];
            bl[n] = *(const short8*)&Bl[col * BK + fq * 8];
        }
#pragma unroll
        for (int m = 0; m < 4; ++m)
#pragma unroll
            for (int n = 0; n < 4; ++n) {
                acc[m][n] = __builtin_amdgcn_mfma_f32_16x16x32_bf16(ah[m], bh[n], acc[m][n], 0, 0, 0);
                acc[m][n] = __builtin_amdgcn_mfma_f32_16x16x32_bf16(ah[m], bl[n], acc[m][n], 0, 0, 0);
                acc[m][n] = __builtin_amdgcn_mfma_f32_16x16x32_bf16(al[m], bh[n], acc[m][n], 0, 0, 0);
            }
        __syncthreads();   // readers done before next overwrite
    }

    // epilogue: C/D layout col=lane&15, row=(lane>>4)*4+reg  [m89/m91]
    const int crow0 = bm * 128 + wr * 64;
    const int ccol0 = bn * 128 + wc * 64;
#pragma unroll
    for (int m = 0; m < 4; ++m) {
        const int row = crow0 + m * 16 + fq * 4;
#pragma unroll
        for (int n = 0; n < 4; ++n) {
            const int col = ccol0 + n * 16 + fr;
#pragma unroll
            for (int j = 0; j < 4; ++j)
                C[(size_t)(row + j) * NE + col] = acc[m][n][j];
        }
    }
}

// ---------------------------------------------------------------------------
// complex pole per state r:  z = exp(lam) * (cos w, sin w),  lam = -5*sigmoid(lraw)
// ---------------------------------------------------------------------------
__device__ inline void pole(const float* __restrict__ lraw, const float* __restrict__ om,
                            int r, float& zr, float& zi, float& lam, float& o)
{
    const float x   = lraw[r];
    const float sig = 1.f / (1.f + expf(-x));
    lam = -5.f * sig;
    o   = om[r];
    const float er = expf(lam);
    zr = er * cosf(o);
    zi = er * sinf(o);
}

// ---------------------------------------------------------------------------
// K2: per-chunk carries — direct coalesced strided reads, unroll-8.
// ---------------------------------------------------------------------------
__global__ __launch_bounds__(256) void carry_kernel(
    const float* __restrict__ C, const float* __restrict__ lraw,
    const float* __restrict__ om, float2* __restrict__ carry)
{
    const int c = blockIdx.x, b = blockIdx.y, r = threadIdx.x;
    const int m0 = b * T_LEN + c * LCH;
    float zr, zi, lam, o;
    pole(lraw, om, r, zr, zi, lam, o);
    const float* p = C + (size_t)m0 * NE + r;
    float hr = 0.f, hi = 0.f;
#pragma unroll 8
    for (int s = 0; s < LCH; ++s) {
        const float u  = p[(size_t)s * NE];
        const float nr = zr * hr - zi * hi + u;
        const float ni = zr * hi + zi * hr;
        hr = nr; hi = ni;
    }
    carry[(size_t)(b * NCH + c) * RS + r] = make_float2(hr, hi);
}

// ---------------------------------------------------------------------------
// K3: prefix over chunks per (b, r), carries bulk-staged through LDS.
// ---------------------------------------------------------------------------
__global__ __launch_bounds__(256) void chunk_scan_kernel(
    const float2* __restrict__ carry, const float* __restrict__ h0r,
    const float* __restrict__ h0i, const float* __restrict__ lraw,
    const float* __restrict__ om, float2* __restrict__ S, float* __restrict__ out)
{
    const int b = blockIdx.x, r = threadIdx.x;
    __shared__ float2 cs[32 * RS];   // 64 KB
    float zr, zi, lam, o;
    pole(lraw, om, r, zr, zi, lam, o);
    const float eL  = expf(lam * (float)LCH);
    const float zLr = eL * cosf(o * (float)LCH);
    const float zLi = eL * sinf(o * (float)LCH);
    float sr = h0r[b * RS + r];
    float si = h0i[b * RS + r];
    for (int half = 0; half < 2; ++half) {
        __syncthreads();
        const float4* src = (const float4*)(carry + ((size_t)b * NCH + half * 32) * RS);
        float4* dst = (float4*)cs;
        for (int i = r; i < 32 * RS / 2; i += 256) dst[i] = src[i];
        __syncthreads();
        for (int cc = 0; cc < 32; ++cc) {
            const int c = half * 32 + cc;
            S[((size_t)b * NCH + c) * RS + r] = make_float2(sr, si);
            const float2 k = cs[cc * RS + r];
            const float nr = zLr * sr - zLi * si + k.x;
            const float ni = zLr * si + zLi * sr + k.y;
            sr = nr; si = ni;
        }
    }
    out[OUT_MAIN + b * RS + r]           = sr;   // final_r
    out[OUT_MAIN + BB * RS + b * RS + r] = si;   // final_i
}

// ---------------------------------------------------------------------------
// K4 v3: re-scan chunk + residual + LayerNorm.
//     Per 8-row batch: flat float4 LDS staging of full C rows (1536 f4, 6/thr),
//     next batch prefetched into regs during compute (T14 issue-early /
//     write-late), scan writes x back into the tile's res slots, LN per wave.
// ---------------------------------------------------------------------------
__global__ __launch_bounds__(256) void scan_ln_kernel(
    const float* __restrict__ C, const float2* __restrict__ S,
    const float* __restrict__ lraw, const float* __restrict__ om,
    const float* __restrict__ gamma, const float* __restrict__ beta,
    float* __restrict__ out)
{
    const int c = blockIdx.x, b = blockIdx.y, r = threadIdx.x;
    __shared__ float tile[8][NE];     // 24 KB: 8 staged rows (flat-contiguous)
    const int m0 = b * T_LEN + c * LCH;
    float zr, zi, lam, o;
    pole(lraw, om, r, zr, zi, lam, o);
    float2 st = S[(size_t)(b * NCH + c) * RS + r];
    const int wid = r >> 6, lane = r & 63;
    const float4 g0  = *(const float4*)&gamma[lane * 8];
    const float4 g1  = *(const float4*)&gamma[lane * 8 + 4];
    const float4 be0 = *(const float4*)&beta[lane * 8];
    const float4 be1 = *(const float4*)&beta[lane * 8 + 4];

    // prologue: stage batch 0
    float4 rv[6];
    {
        const float4* src = (const float4*)(C + (size_t)m0 * NE);
#pragma unroll
        for (int k = 0; k < 6; ++k) rv[k] = src[r + 256 * k];
#pragma unroll
        for (int k = 0; k < 6; ++k) ((float4*)tile)[r + 256 * k] = rv[k];
    }

    for (int batch = 0; batch < 4; ++batch) {
        __syncthreads();   // staged writes visible
        // issue next batch's loads early — hidden under scan + LN
        if (batch < 3) {
            const float4* src = (const float4*)(C + (size_t)(m0 + (batch + 1) * 8) * NE);
#pragma unroll
            for (int k = 0; k < 6; ++k) rv[k] = src[r + 256 * k];
        }
        // scan phase: thread r owns state r; write x into the tile's res slots
#pragma unroll
        for (int s = 0; s < 8; ++s) {
            const float u  = tile[s][r];
            const float hr = zr * st.x - zi * st.y + u;
            const float hi = zr * st.y + zi * st.x;
            st.x = hr; st.y = hi;
            tile[s][256 + r] = hr + tile[s][256 + r];
            tile[s][512 + r] = hi + tile[s][512 + r];
        }
        __syncthreads();   // x visible
        // LN phase: wave w owns rows w*2, w*2+1
#pragma unroll
        for (int rr = 0; rr < 2; ++rr) {
            const int s = wid * 2 + rr;
            const int m = m0 + batch * 8 + s;
            const float4 x0 = *(const float4*)&tile[s][256 + lane * 8];
            const float4 x1 = *(const float4*)&tile[s][256 + lane * 8 + 4];
            float s1 = (x0.x + x0.y) + (x0.z + x0.w) + (x1.x + x1.y) + (x1.z + x1.w);
            float s2 = (x0.x * x0.x + x0.y * x0.y) + (x0.z * x0.z + x0.w * x0.w)
                     + (x1.x * x1.x + x1.y * x1.y) + (x1.z * x1.z + x1.w * x1.w);
#pragma unroll
            for (int off = 1; off < 64; off <<= 1) {
                s1 += __shfl_xor(s1, off);
                s2 += __shfl_xor(s2, off);
            }
            const float mu   = s1 * (1.f / 512.f);
            const float var  = s2 * (1.f / 512.f) - mu * mu;
            const float rstd = rsqrtf(var + 1e-5f);
            float4 o0, o1;
            o0.x = (x0.x - mu) * rstd * g0.x + be0.x;
            o0.y = (x0.y - mu) * rstd * g0.y + be0.y;
            o0.z = (x0.z - mu) * rstd * g0.z + be0.z;
            o0.w = (x0.w - mu) * rstd * g0.w + be0.w;
            o1.x = (x1.x - mu) * rstd * g1.x + be1.x;
            o1.y = (x1.y - mu) * rstd * g1.y + be1.y;
            o1.z = (x1.z - mu) * rstd * g1.z + be1.z;
            o1.w = (x1.w - mu) * rstd * g1.w + be1.w;
            *(float4*)&out[(size_t)m * 512 + lane * 8]     = o0;
            *(float4*)&out[(size_t)m * 512 + lane * 8 + 4] = o1;
        }
        __syncthreads();   // LN reads done before overwrite
        if (batch < 3) {
#pragma unroll
            for (int k = 0; k < 6; ++k) ((float4*)tile)[r + 256 * k] = rv[k];
        }
    }
}

// ---------------------------------------------------------------------------
extern "C" void kernel_launch(void* const* d_in, const int* in_sizes, int n_in,
                              void* d_out, int out_size, void* d_ws, size_t ws_size,
                              hipStream_t stream)
{
    const float* u    = (const float*)d_in[0];
    const float* h0r  = (const float*)d_in[1];
    const float* h0i  = (const float*)d_in[2];
    const float* lraw = (const float*)d_in[3];
    const float* omg  = (const float*)d_in[4];
    const float* Wp   = (const float*)d_in[5];
    const float* Wr   = (const float*)d_in[6];
    const float* gam  = (const float*)d_in[7];
    const float* bet  = (const float*)d_in[8];
    float* out = (float*)d_out;

    // workspace layout (~123 MB):
    float*  C     = (float*)d_ws;                       // 16384*768 f32 (50.3 MB)
    float2* carry = (float2*)(C + (size_t)M_TOT * NE);  // 1 MB
    float2* S     = carry + (size_t)BB * NCH * RS;      // 1 MB
    ushort* Uhi   = (ushort*)(S + (size_t)BB * NCH * RS);
    ushort* Ulo   = Uhi + (size_t)M_TOT * DIN;          // 33.5 MB each
    ushort* Whi   = Ulo + (size_t)M_TOT * DIN;          // 1.57 MB
    ushort* Wlo   = Whi + (size_t)NE * DIN;             // 1.57 MB

    split_kernel<<<N8TOT / 256, 256, 0, stream>>>(u, Wp, Wr, Uhi, Ulo, Whi, Wlo);
    gemm_mfma<<<dim3(NE / 128, M_TOT / 128), 256, 0, stream>>>(Uhi, Ulo, Whi, Wlo, C);
    carry_kernel<<<dim3(NCH, BB), 256, 0, stream>>>(C, lraw, omg, carry);
    chunk_scan_kernel<<<BB, 256, 0, stream>>>(carry, h0r, h0i, lraw, omg, S, out);
    scan_ln_kernel<<<dim3(NCH, BB), 256, 0, stream>>>(C, (const float2*)S, lraw, omg, gam, bet, out);
}

// Round 5
// 227.000 us; speedup vs baseline: 1.1575x; 1.1390x over previous
//
#include <hip/hip_runtime.h>
#include <math.h>

// Problem constants
#define T_LEN 2048
#define BB    8
#define RS    256
#define DIN   1024
#define NE    768                 // 256 (W_proj) + 512 (W_res)
#define M_TOT (BB * T_LEN)        // 16384
#define LCH   32                  // scan chunk length
#define NCH   (T_LEN / LCH)       // 64 chunks
#define OUT_MAIN (M_TOT * 512)    // 8388608 floats, then final_r (2048), final_i (2048)

typedef unsigned short ushort;
typedef unsigned int   uint;
typedef short  short8  __attribute__((ext_vector_type(8)));
typedef float  f32x4   __attribute__((ext_vector_type(4)));
typedef ushort ushort8 __attribute__((ext_vector_type(8)));

// round-to-nearest-even fp32 -> bf16 bits
__device__ __forceinline__ ushort f2bf_rn(float x) {
    uint u = __float_as_uint(x);
    return (ushort)((u + 0x7FFFu + ((u >> 16) & 1u)) >> 16);
}
__device__ __forceinline__ float bf2f(ushort b) {
    return __uint_as_float(((uint)b) << 16);
}

// async global->LDS, 16 bytes per lane (lane-linear LDS dest required)
__device__ __forceinline__ void gload16(const ushort* g, ushort* l) {
    __builtin_amdgcn_global_load_lds(
        (const __attribute__((address_space(1))) uint*)g,
        (__attribute__((address_space(3))) uint*)l, 16, 0, 0);
}

// ---------------------------------------------------------------------------
// K0: fused split fp32 -> bf16 hi/lo for U, W_proj, W_res in one launch.
// ---------------------------------------------------------------------------
#define N8U  (M_TOT * DIN / 8)        // 2097152
#define N8WP (RS * DIN / 8)           // 32768
#define N8WR (2 * RS * DIN / 8)       // 65536
#define N8TOT (N8U + N8WP + N8WR)     // 2195456 = 8576 * 256

__global__ __launch_bounds__(256) void split_kernel(
    const float* __restrict__ u, const float* __restrict__ wp,
    const float* __restrict__ wr, ushort* __restrict__ Uhi,
    ushort* __restrict__ Ulo, ushort* __restrict__ Whi, ushort* __restrict__ Wlo)
{
    const int i = blockIdx.x * 256 + threadIdx.x;
    if (i >= N8TOT) return;
    const float* src; ushort* hi; ushort* lo; int j;
    if (i < N8U)              { src = u;  hi = Uhi; lo = Ulo; j = i; }
    else if (i < N8U + N8WP)  { src = wp; hi = Whi; lo = Wlo; j = i - N8U; }
    else                      { src = wr; hi = Whi + (size_t)RS * DIN;
                                lo = Wlo + (size_t)RS * DIN; j = i - N8U - N8WP; }
    const float4 x0 = ((const float4*)src)[(size_t)j * 2 + 0];
    const float4 x1 = ((const float4*)src)[(size_t)j * 2 + 1];
    const float xs[8] = {x0.x, x0.y, x0.z, x0.w, x1.x, x1.y, x1.z, x1.w};
    ushort8 hv, lv;
#pragma unroll
    for (int k = 0; k < 8; ++k) {
        const ushort hb = f2bf_rn(xs[k]);
        hv[k] = hb;
        lv[k] = f2bf_rn(xs[k] - bf2f(hb));
    }
    ((ushort8*)hi)[j] = hv;
    ((ushort8*)lo)[j] = lv;
}

// ---------------------------------------------------------------------------
// K1: bf16 3-term split MFMA GEMM — R2 structure (measured 859 TF eff) +
//     bijective XCD swizzle (768 = 8 * 96) for L2 A-panel reuse.
//     128x128 tile, BK=32, 4 waves, 4x4 16x16x32 frags, global_load_lds w=16,
//     2-barrier K-loop, 32 KB LDS.
// ---------------------------------------------------------------------------
#define Bb 128
#define BK 32

__global__ __launch_bounds__(256) void gemm_mfma(
    const ushort* __restrict__ Uh, const ushort* __restrict__ Ul,
    const ushort* __restrict__ Wh, const ushort* __restrict__ Wl,
    float* __restrict__ C)
{
    __shared__ ushort Ah[Bb * BK], Al[Bb * BK], Bh[Bb * BK], Bl[Bb * BK];
    const int tid  = threadIdx.x;
    const int id   = blockIdx.x;
    const int sid  = (id & 7) * 96 + (id >> 3);   // XCD-contiguous, bijective
    const int bn   = sid % 6;
    const int bm   = sid / 6;
    const int wid  = tid >> 6;
    const int lane = tid & 63;
    const int wr   = wid >> 1, wc = wid & 1;
    const int fr   = lane & 15;           // row/col within fragment
    const int fq   = lane >> 4;           // k-chunk 0..3

    const int srow = tid >> 2;            // 0..63
    const int skk  = (tid & 3) * 8;
    const ushort* gAh = Uh + (size_t)(bm * 128 + srow) * DIN + skk;
    const ushort* gAl = Ul + (size_t)(bm * 128 + srow) * DIN + skk;
    const ushort* gBh = Wh + (size_t)(bn * 128 + srow) * DIN + skk;
    const ushort* gBl = Wl + (size_t)(bn * 128 + srow) * DIN + skk;
    ushort* lAh0 = Ah + tid * 8; ushort* lAh1 = Ah + 64 * BK + tid * 8;
    ushort* lAl0 = Al + tid * 8; ushort* lAl1 = Al + 64 * BK + tid * 8;
    ushort* lBh0 = Bh + tid * 8; ushort* lBh1 = Bh + 64 * BK + tid * 8;
    ushort* lBl0 = Bl + tid * 8; ushort* lBl1 = Bl + 64 * BK + tid * 8;
    const size_t rstep = (size_t)64 * DIN;

    f32x4 acc[4][4];
#pragma unroll
    for (int m = 0; m < 4; ++m)
#pragma unroll
        for (int n = 0; n < 4; ++n) acc[m][n] = (f32x4){0.f, 0.f, 0.f, 0.f};

    for (int kk = 0; kk < DIN; kk += BK) {
        gload16(gAh + kk, lAh0); gload16(gAh + kk + rstep, lAh1);
        gload16(gAl + kk, lAl0); gload16(gAl + kk + rstep, lAl1);
        gload16(gBh + kk, lBh0); gload16(gBh + kk + rstep, lBh1);
        gload16(gBl + kk, lBl0); gload16(gBl + kk + rstep, lBl1);
        __syncthreads();   // drains vmcnt (compiler-emitted) — tiles ready

        short8 ah[4], al[4], bh[4], bl[4];
#pragma unroll
        for (int m = 0; m < 4; ++m) {
            const int row = wr * 64 + m * 16 + fr;
            ah[m] = *(const short8*)&Ah[row * BK + fq * 8];
            al[m] = *(const short8*)&Al[row * BK + fq * 8];
        }
#pragma unroll
        for (int n = 0; n < 4; ++n) {
            const int col = wc * 64 + n * 16 + fr;
            bh[n] = *(const short8*)&Bh[col * BK + fq * 8];
            bl[n] = *(const short8*)&Bl[col * BK + fq * 8];
        }
#pragma unroll
        for (int m = 0; m < 4; ++m)
#pragma unroll
            for (int n = 0; n < 4; ++n) {
                acc[m][n] = __builtin_amdgcn_mfma_f32_16x16x32_bf16(ah[m], bh[n], acc[m][n], 0, 0, 0);
                acc[m][n] = __builtin_amdgcn_mfma_f32_16x16x32_bf16(ah[m], bl[n], acc[m][n], 0, 0, 0);
                acc[m][n] = __builtin_amdgcn_mfma_f32_16x16x32_bf16(al[m], bh[n], acc[m][n], 0, 0, 0);
            }
        __syncthreads();   // readers done before next overwrite
    }

    // epilogue: C/D layout col=lane&15, row=(lane>>4)*4+reg  [m89/m91]
    const int crow0 = bm * 128 + wr * 64;
    const int ccol0 = bn * 128 + wc * 64;
#pragma unroll
    for (int m = 0; m < 4; ++m) {
        const int row = crow0 + m * 16 + fq * 4;
#pragma unroll
        for (int n = 0; n < 4; ++n) {
            const int col = ccol0 + n * 16 + fr;
#pragma unroll
            for (int j = 0; j < 4; ++j)
                C[(size_t)(row + j) * NE + col] = acc[m][n][j];
        }
    }
}

// ---------------------------------------------------------------------------
// complex pole per state r:  z = exp(lam) * (cos w, sin w),  lam = -5*sigmoid(lraw)
// ---------------------------------------------------------------------------
__device__ inline void pole(const float* __restrict__ lraw, const float* __restrict__ om,
                            int r, float& zr, float& zi, float& lam, float& o)
{
    const float x   = lraw[r];
    const float sig = 1.f / (1.f + expf(-x));
    lam = -5.f * sig;
    o   = om[r];
    const float er = expf(lam);
    zr = er * cosf(o);
    zi = er * sinf(o);
}

// ---------------------------------------------------------------------------
// K2: per-chunk carries — direct coalesced strided reads, unroll-8.
// ---------------------------------------------------------------------------
__global__ __launch_bounds__(256) void carry_kernel(
    const float* __restrict__ C, const float* __restrict__ lraw,
    const float* __restrict__ om, float2* __restrict__ carry)
{
    const int c = blockIdx.x, b = blockIdx.y, r = threadIdx.x;
    const int m0 = b * T_LEN + c * LCH;
    float zr, zi, lam, o;
    pole(lraw, om, r, zr, zi, lam, o);
    const float* p = C + (size_t)m0 * NE + r;
    float hr = 0.f, hi = 0.f;
#pragma unroll 8
    for (int s = 0; s < LCH; ++s) {
        const float u  = p[(size_t)s * NE];
        const float nr = zr * hr - zi * hi + u;
        const float ni = zr * hi + zi * hr;
        hr = nr; hi = ni;
    }
    carry[(size_t)(b * NCH + c) * RS + r] = make_float2(hr, hi);
}

// ---------------------------------------------------------------------------
// K3: fused prefix + re-scan + residual + LayerNorm (R3-v2 body).
//     Phase A: block (c,b) computes its own entry state
//        S(c) = h0 * zL^c + sum_{j<c} zL^(c-1-j) * carry_j
//     (coalesced carry loads, ~8c VALU/thread) — replaces the serial
//     8-block chunk_scan kernel and one launch.
//     Phase B: R3-v2 scan+LN (measured-best). Block c=63 writes finals.
// ---------------------------------------------------------------------------
__global__ __launch_bounds__(256) void scan_ln_kernel(
    const float* __restrict__ C, const float2* __restrict__ carry,
    const float* __restrict__ h0r, const float* __restrict__ h0i,
    const float* __restrict__ lraw, const float* __restrict__ om,
    const float* __restrict__ gamma, const float* __restrict__ beta,
    float* __restrict__ out)
{
    const int c = blockIdx.x, b = blockIdx.y, r = threadIdx.x;
    __shared__ float xt[8][512];
    const int m0 = b * T_LEN + c * LCH;
    float zr, zi, lam, o;
    pole(lraw, om, r, zr, zi, lam, o);

    // ---- phase A: entry state for this chunk ----
    const float eL  = expf(lam * (float)LCH);
    const float zLr = eL * cosf(o * (float)LCH);
    const float zLi = eL * sinf(o * (float)LCH);
    float ar = 0.f, ai = 0.f;           // sum_{j<c} zL^(c-1-j) carry_j
    const float2* cp = carry + (size_t)b * NCH * RS + r;
    for (int j = 0; j < c; ++j) {
        const float2 k = cp[(size_t)j * RS];
        const float nr = zLr * ar - zLi * ai + k.x;
        const float ni = zLr * ai + zLi * ar + k.y;
        ar = nr; ai = ni;
    }
    const float tL  = (float)(LCH * c);
    const float dz  = expf(lam * tL);   // underflow to 0 for large c is fine
    const float pzr = dz * cosf(o * tL);
    const float pzi = dz * sinf(o * tL);
    const float h0R = h0r[b * RS + r];
    const float h0I = h0i[b * RS + r];
    float2 st;
    st.x = ar + h0R * pzr - h0I * pzi;
    st.y = ai + h0R * pzi + h0I * pzr;

    // ---- phase B: re-scan + residual + LN (R3-v2, measured best) ----
    const int wid = r >> 6, lane = r & 63;
    const float4 g0  = *(const float4*)&gamma[lane * 8];
    const float4 g1  = *(const float4*)&gamma[lane * 8 + 4];
    const float4 be0 = *(const float4*)&beta[lane * 8];
    const float4 be1 = *(const float4*)&beta[lane * 8 + 4];

    for (int batch = 0; batch < 4; ++batch) {
        const int s0 = batch * 8;
#pragma unroll
        for (int s = 0; s < 8; ++s) {
            const int m = m0 + s0 + s;
            const float u  = C[(size_t)m * NE + r];
            const float hr = zr * st.x - zi * st.y + u;
            const float hi = zr * st.y + zi * st.x;
            st.x = hr; st.y = hi;
            xt[s][r]       = hr + C[(size_t)m * NE + 256 + r];
            xt[s][256 + r] = hi + C[(size_t)m * NE + 512 + r];
        }
        __syncthreads();
#pragma unroll
        for (int rr = 0; rr < 2; ++rr) {
            const int s = wid * 2 + rr;
            const int m = m0 + s0 + s;
            const float4 x0 = *(const float4*)&xt[s][lane * 8];
            const float4 x1 = *(const float4*)&xt[s][lane * 8 + 4];
            float s1 = (x0.x + x0.y) + (x0.z + x0.w) + (x1.x + x1.y) + (x1.z + x1.w);
            float s2 = (x0.x * x0.x + x0.y * x0.y) + (x0.z * x0.z + x0.w * x0.w)
                     + (x1.x * x1.x + x1.y * x1.y) + (x1.z * x1.z + x1.w * x1.w);
#pragma unroll
            for (int off = 1; off < 64; off <<= 1) {
                s1 += __shfl_xor(s1, off);
                s2 += __shfl_xor(s2, off);
            }
            const float mu   = s1 * (1.f / 512.f);
            const float var  = s2 * (1.f / 512.f) - mu * mu;
            const float rstd = rsqrtf(var + 1e-5f);
            float4 o0, o1;
            o0.x = (x0.x - mu) * rstd * g0.x + be0.x;
            o0.y = (x0.y - mu) * rstd * g0.y + be0.y;
            o0.z = (x0.z - mu) * rstd * g0.z + be0.z;
            o0.w = (x0.w - mu) * rstd * g0.w + be0.w;
            o1.x = (x1.x - mu) * rstd * g1.x + be1.x;
            o1.y = (x1.y - mu) * rstd * g1.y + be1.y;
            o1.z = (x1.z - mu) * rstd * g1.z + be1.z;
            o1.w = (x1.w - mu) * rstd * g1.w + be1.w;
            *(float4*)&out[(size_t)m * 512 + lane * 8]     = o0;
            *(float4*)&out[(size_t)m * 512 + lane * 8 + 4] = o1;
        }
        __syncthreads();   // xt reuse next batch
    }

    if (c == NCH - 1) {   // st = h[T-1]
        out[OUT_MAIN + b * RS + r]           = st.x;   // final_r
        out[OUT_MAIN + BB * RS + b * RS + r] = st.y;   // final_i
    }
}

// ---------------------------------------------------------------------------
extern "C" void kernel_launch(void* const* d_in, const int* in_sizes, int n_in,
                              void* d_out, int out_size, void* d_ws, size_t ws_size,
                              hipStream_t stream)
{
    const float* u    = (const float*)d_in[0];
    const float* h0r  = (const float*)d_in[1];
    const float* h0i  = (const float*)d_in[2];
    const float* lraw = (const float*)d_in[3];
    const float* omg  = (const float*)d_in[4];
    const float* Wp   = (const float*)d_in[5];
    const float* Wr   = (const float*)d_in[6];
    const float* gam  = (const float*)d_in[7];
    const float* bet  = (const float*)d_in[8];
    float* out = (float*)d_out;

    // workspace layout (~122 MB):
    float*  C     = (float*)d_ws;                       // 16384*768 f32 (50.3 MB)
    float2* carry = (float2*)(C + (size_t)M_TOT * NE);  // 1 MB
    ushort* Uhi   = (ushort*)(carry + (size_t)BB * NCH * RS);
    ushort* Ulo   = Uhi + (size_t)M_TOT * DIN;          // 33.5 MB each
    ushort* Whi   = Ulo + (size_t)M_TOT * DIN;          // 1.57 MB
    ushort* Wlo   = Whi + (size_t)NE * DIN;             // 1.57 MB

    split_kernel<<<N8TOT / 256, 256, 0, stream>>>(u, Wp, Wr, Uhi, Ulo, Whi, Wlo);
    gemm_mfma<<<768, 256, 0, stream>>>(Uhi, Ulo, Whi, Wlo, C);
    carry_kernel<<<dim3(NCH, BB), 256, 0, stream>>>(C, lraw, omg, carry);
    scan_ln_kernel<<<dim3(NCH, BB), 256, 0, stream>>>(C, (const float2*)carry,
                                                      h0r, h0i, lraw, omg, gam, bet, out);
}